// Round 4
// baseline (67.812 us; speedup 1.0000x reference)
//
#include <hip/hip_runtime.h>

// ROI Align fp32, B=2 C=256 H=W=100, K ROIs, PH=PW=7, SR=2, scale=0.125
// Round 4: workgroup-cooperative LDS staging. WG (256T) = one (roi, 8-ch
// group). Stage ROI bbox (<=26 x <=32, clipped to Hs x Wn) coalesced into
// LDS, then lane=bin computes 2 channels/wave from LDS (ds_read2 merged).
// Moves the bilinear tap scatter from the TA/L1 pipe onto the LDS pipe.

#define ROI_PH 7
#define ROI_PW 7
#define ROI_NBIN 49
#define ROI_SCALE 0.125f

constexpr int kC = 256;
constexpr int kH = 100;
constexpr int kW = 100;
constexpr int kPlane = kH * kW;   // 10000
constexpr int kCPG = 8;           // channels per workgroup
constexpr int kGPK = kC / kCPG;   // 32 groups per roi
constexpr int kRows = 26;         // max bbox rows: 12*bh2<=21.4 -> diff<=22, +4
constexpr int kPitch = 36;        // row pitch (floats): 144B = 16B-aligned, +4 banks/row

typedef float f32x4 __attribute__((ext_vector_type(4)));

__device__ inline f32x4 ld4(const float* p) {
    f32x4 v;
    __builtin_memcpy(&v, p, 16);
    return v;
}

// window base for one axis, from the bin's FIRST sample (same rule as
// axis_weights, so bbox [base(bin0) .. base(bin6)+3] covers every bin).
__device__ inline int axis_base(float g, int dim) {
    const float c = fminf(fmaxf(g, 0.0f), (float)(dim - 1));
    return min((int)floorf(c), dim - 4);
}

// 4-slot tap-scatter weights for one axis (two samples, bilinear each).
__device__ inline void axis_weights(float g0, float g1, int dim,
                                    int& base, float w[4]) {
    const float v0 = (g0 >= -1.0f && g0 <= (float)dim) ? 1.0f : 0.0f;
    const float v1 = (g1 >= -1.0f && g1 <= (float)dim) ? 1.0f : 0.0f;
    const float c0 = fminf(fmaxf(g0, 0.0f), (float)(dim - 1));
    const float c1 = fminf(fmaxf(g1, 0.0f), (float)(dim - 1));
    const int i0 = (int)floorf(c0);
    const int j0 = (int)floorf(c1);
    const int i1 = min(i0 + 1, dim - 1);
    const int j1 = min(j0 + 1, dim - 1);
    const float l0 = c0 - (float)i0;
    const float l1 = c1 - (float)j0;
    const float tw0 = (1.0f - l0) * v0;
    const float tw1 = l0 * v0;
    const float tw2 = (1.0f - l1) * v1;
    const float tw3 = l1 * v1;
    base = min(i0, dim - 4);
#pragma unroll
    for (int d = 0; d < 4; ++d) {
        const int idx = base + d;
        float acc = 0.0f;
        acc += (i0 == idx) ? tw0 : 0.0f;
        acc += (i1 == idx) ? tw1 : 0.0f;
        acc += (j0 == idx) ? tw2 : 0.0f;
        acc += (j1 == idx) ? tw3 : 0.0f;
        w[d] = acc;
    }
}

__global__ __launch_bounds__(256) void roi_align_fwd(
    const float* __restrict__ feat,
    const float* __restrict__ rois,
    float* __restrict__ out,
    int K)
{
    __shared__ float lds[kCPG][kRows][kPitch];   // 29952 B -> 5 blocks/CU

    const int k  = blockIdx.x >> 5;              // roi
    const int cg = blockIdx.x & (kGPK - 1);      // 8-channel group

    // ROI params (block-uniform address -> scalar loads)
    const float* r = rois + (size_t)k * 5;
    const int   bidx = (int)r[0];
    const float x1v = r[1] * ROI_SCALE;
    const float y1v = r[2] * ROI_SCALE;
    const float x2v = r[3] * ROI_SCALE;
    const float y2v = r[4] * ROI_SCALE;
    const float bw2 = fmaxf(x2v - x1v, 1.0f) * (0.5f / ROI_PW);
    const float bh2 = fmaxf(y2v - y1v, 1.0f) * (0.5f / ROI_PH);

    // bbox of all bins' 4x4 windows (bases monotone in ph/pw)
    const int yb0 = axis_base(y1v + 0.5f  * bh2, kH);
    const int yb6 = axis_base(y1v + 12.5f * bh2, kH);
    const int xb0 = axis_base(x1v + 0.5f  * bw2, kW);
    const int xb6 = axis_base(x1v + 12.5f * bw2, kW);
    const int xbl = min(xb0, kW - 32);           // keep 32-wide loads in-row
    const int Hs  = yb6 + 4 - yb0;               // <= 26
    const int Wn  = xb6 + 4 - xbl;               // <= 32

    // ---- stage: thread -> (c, rr, xq); rows looped 4 at a time ----
    {
        const int c  = threadIdx.x >> 5;         // 0..7
        const int rr = (threadIdx.x >> 3) & 3;   // 0..3
        const int xq = (threadIdx.x & 7) << 2;   // 0,4,..,28
        if (xq < Wn) {
            const float* sp = feat
                + ((size_t)(bidx * kC + cg * kCPG + c)) * kPlane
                + (size_t)(yb0 * kW + xbl + xq);
#pragma unroll
            for (int p = 0; p < 7; ++p) {
                const int row = p * 4 + rr;
                if (row < Hs) {
                    *reinterpret_cast<f32x4*>(&lds[c][row][xq]) = ld4(sp + row * kW);
                }
            }
        }
    }
    __syncthreads();

    // ---- compute: lane = bin, wave handles 2 channels ----
    const int lane = threadIdx.x & 63;
    const int wave = threadIdx.x >> 6;
    const bool active = lane < ROI_NBIN;
    const int bin = active ? lane : (ROI_NBIN - 1);
    const int ph = bin / ROI_PW;
    const int pw = bin - ph * ROI_PW;

    const float gy0 = y1v + ((float)(2 * ph) + 0.5f) * bh2;
    const float gy1 = y1v + ((float)(2 * ph) + 1.5f) * bh2;
    const float gx0 = x1v + ((float)(2 * pw) + 0.5f) * bw2;
    const float gx1 = x1v + ((float)(2 * pw) + 1.5f) * bw2;

    int ybase, xbase;
    float wy[4], wx[4];
    axis_weights(gy0, gy1, kH, ybase, wy);
    axis_weights(gx0, gx1, kW, xbase, wx);

    float wgt[4][4];
#pragma unroll
    for (int dy = 0; dy < 4; ++dy) {
        const float wyq = wy[dy] * 0.25f;
#pragma unroll
        for (int dx = 0; dx < 4; ++dx) wgt[dy][dx] = wyq * wx[dx];
    }

    const int ry = ybase - yb0;                  // 0..22
    const int rx = xbase - xbl;                  // 0..28
    const int c0 = wave * 2;

    float acc0 = 0.0f, acc1 = 0.0f;
#pragma unroll
    for (int dy = 0; dy < 4; ++dy) {
#pragma unroll
        for (int dx = 0; dx < 4; ++dx) {
            const float w = wgt[dy][dx];
            acc0 += w * lds[c0    ][ry + dy][rx + dx];
            acc1 += w * lds[c0 + 1][ry + dy][rx + dx];
        }
    }

    if (active) {
        float* outp = out + ((size_t)k * kC + (size_t)(cg * kCPG + c0)) * ROI_NBIN + bin;
        outp[0] = acc0;
        outp[ROI_NBIN] = acc1;
    }
}

extern "C" void kernel_launch(void* const* d_in, const int* in_sizes, int n_in,
                              void* d_out, int out_size, void* d_ws, size_t ws_size,
                              hipStream_t stream) {
    const float* feat = (const float*)d_in[0];
    const float* rois = (const float*)d_in[1];
    float* out = (float*)d_out;
    const int K = in_sizes[1] / 5;               // 1000

    roi_align_fwd<<<K * kGPK, 256, 0, stream>>>(feat, rois, out, K);
}

// Round 5
// 46.034 us; speedup vs baseline: 1.4731x; 1.4731x over previous
//
#include <hip/hip_runtime.h>

// ROI Align fp32, B=2 C=256 H=W=100, K ROIs, PH=PW=7, SR=2, scale=0.125
// Round 5: one-time NCHW->NHWC(bf16) transpose into d_ws, then gather with
// lane=channel (perfectly coalesced 256B loads, no TA address divergence).
// Per-bin weights computed once per block into LDS; output transposed through
// LDS so global writes stay coalesced. Fallback to the round-2 kernel if
// ws_size is too small for the transposed map.

#define ROI_PH 7
#define ROI_PW 7
#define ROI_NBIN 49
#define ROI_SCALE 0.125f

constexpr int kB = 2;
constexpr int kC = 256;
constexpr int kH = 100;
constexpr int kW = 100;
constexpr int kPlane = kH * kW;          // 10000
constexpr int kPixGroups = (kPlane + 63) / 64;  // 157

typedef float f32x4 __attribute__((ext_vector_type(4)));

__device__ inline f32x4 ld4(const float* p) {
    f32x4 v;
    __builtin_memcpy(&v, p, 16);
    return v;
}

// 4-slot tap-scatter weights for one axis (two samples, bilinear each).
__device__ inline void axis_weights(float g0, float g1, int dim,
                                    int& base, float w[4]) {
    const float v0 = (g0 >= -1.0f && g0 <= (float)dim) ? 1.0f : 0.0f;
    const float v1 = (g1 >= -1.0f && g1 <= (float)dim) ? 1.0f : 0.0f;
    const float c0 = fminf(fmaxf(g0, 0.0f), (float)(dim - 1));
    const float c1 = fminf(fmaxf(g1, 0.0f), (float)(dim - 1));
    const int i0 = (int)floorf(c0);
    const int j0 = (int)floorf(c1);
    const int i1 = min(i0 + 1, dim - 1);
    const int j1 = min(j0 + 1, dim - 1);
    const float l0 = c0 - (float)i0;
    const float l1 = c1 - (float)j0;
    const float tw0 = (1.0f - l0) * v0;
    const float tw1 = l0 * v0;
    const float tw2 = (1.0f - l1) * v1;
    const float tw3 = l1 * v1;
    base = min(i0, dim - 4);
#pragma unroll
    for (int d = 0; d < 4; ++d) {
        const int idx = base + d;
        float acc = 0.0f;
        acc += (i0 == idx) ? tw0 : 0.0f;
        acc += (i1 == idx) ? tw1 : 0.0f;
        acc += (j0 == idx) ? tw2 : 0.0f;
        acc += (j1 == idx) ? tw3 : 0.0f;
        w[d] = acc;
    }
}

// ---------------- Kernel 1: NCHW fp32 -> NHWC bf16 (packed pairs) ----------
// Block = 64 pixels of one batch image; LDS-tiled so both global sides are
// coalesced. Output dword = bf16(ch even) | bf16(ch odd)<<16, RNE rounding.
__global__ __launch_bounds__(256) void nchw_to_nhwc_bf16(
    const float* __restrict__ feat,
    unsigned int* __restrict__ wsp)
{
    __shared__ unsigned int tile[64][130];   // pitch 130 dwords: even, +2 bank rot

    const int blk  = blockIdx.x;
    const int b    = blk / kPixGroups;
    const int pg   = blk - b * kPixGroups;
    const int pix0 = pg * 64;
    const int lane = threadIdx.x & 63;
    const int wv   = threadIdx.x >> 6;

    const int  px_in = pix0 + lane;
    const bool okin  = px_in < kPlane;
    const float* fb  = feat + (size_t)b * kC * kPlane;

#pragma unroll 4
    for (int i = 0; i < 32; ++i) {
        const int cd = wv + 4 * i;           // channel-pair index 0..127
        const int c0 = cd * 2;
        const float f0 = okin ? fb[(size_t)c0 * kPlane + px_in] : 0.0f;
        const float f1 = okin ? fb[(size_t)(c0 + 1) * kPlane + px_in] : 0.0f;
        unsigned int u0 = __float_as_uint(f0);
        unsigned int u1 = __float_as_uint(f1);
        u0 += 0x7fffu + ((u0 >> 16) & 1u);   // RNE to bf16
        u1 += 0x7fffu + ((u1 >> 16) & 1u);
        tile[lane][cd] = (u0 >> 16) | (u1 & 0xffff0000u);
    }
    __syncthreads();

#pragma unroll 4
    for (int j = 0; j < 16; ++j) {
        const int px = j * 4 + wv;
        if (pix0 + px < kPlane) {
            const uint2 v = *reinterpret_cast<const uint2*>(&tile[px][lane * 2]);
            *reinterpret_cast<uint2*>(
                wsp + ((size_t)(b * kPlane + pix0 + px)) * 128 + lane * 2) = v;
        }
    }
}

// ---------------- Kernel 2: ROI align from NHWC bf16 -----------------------
// Block = (roi, 128-channel half). lane = channel-pair -> every tap load is a
// coalesced 256B global_load_dword. Weights once per block into LDS; output
// staged in LDS tile so stores are coalesced.
__global__ __launch_bounds__(256) void roi_align_nhwc(
    const unsigned int* __restrict__ wsp,
    const float* __restrict__ rois,
    float* __restrict__ out,
    int K)
{
    __shared__ float owgt[ROI_NBIN][16];
    __shared__ int   opix[ROI_NBIN];
    __shared__ float otile[128][ROI_NBIN];

    const int k    = blockIdx.x >> 1;
    const int half = blockIdx.x & 1;

    const float* r = rois + (size_t)k * 5;
    const int   bidx = (int)r[0];
    const float x1v = r[1] * ROI_SCALE;
    const float y1v = r[2] * ROI_SCALE;
    const float x2v = r[3] * ROI_SCALE;
    const float y2v = r[4] * ROI_SCALE;
    const float bw2 = fmaxf(x2v - x1v, 1.0f) * (0.5f / ROI_PW);
    const float bh2 = fmaxf(y2v - y1v, 1.0f) * (0.5f / ROI_PH);

    // phase 1: 49 threads build per-bin 4x4 weights + window base pixel
    if (threadIdx.x < ROI_NBIN) {
        const int bin = threadIdx.x;
        const int ph = bin / ROI_PW;
        const int pw = bin - ph * ROI_PW;
        const float gy0 = y1v + ((float)(2 * ph) + 0.5f) * bh2;
        const float gy1 = y1v + ((float)(2 * ph) + 1.5f) * bh2;
        const float gx0 = x1v + ((float)(2 * pw) + 0.5f) * bw2;
        const float gx1 = x1v + ((float)(2 * pw) + 1.5f) * bw2;
        int ybase, xbase;
        float wy[4], wx[4];
        axis_weights(gy0, gy1, kH, ybase, wy);
        axis_weights(gx0, gx1, kW, xbase, wx);
#pragma unroll
        for (int dy = 0; dy < 4; ++dy) {
            const float wyq = wy[dy] * 0.25f;
#pragma unroll
            for (int dx = 0; dx < 4; ++dx) owgt[bin][dy * 4 + dx] = wyq * wx[dx];
        }
        opix[bin] = ybase * kW + xbase;
    }
    __syncthreads();

    const int lane = threadIdx.x & 63;
    const int wv   = threadIdx.x >> 6;
    const unsigned int* base = wsp + (size_t)bidx * kPlane * 128 + half * 64 + lane;

    // phase 2: each wave computes bins wv, wv+4, wv+8, ... (all 128 ch)
#pragma unroll
    for (int i = 0; i < 13; ++i) {
        const int bin = i * 4 + wv;
        if (bin < ROI_NBIN) {
            float wq[4][4];
#pragma unroll
            for (int dy = 0; dy < 4; ++dy) {
                const f32x4 wrow = *reinterpret_cast<const f32x4*>(&owgt[bin][dy * 4]);
#pragma unroll
                for (int dx = 0; dx < 4; ++dx) wq[dy][dx] = wrow[dx];
            }
            const unsigned int* p = base + (size_t)opix[bin] * 128;
            float acc0 = 0.0f, acc1 = 0.0f;
#pragma unroll
            for (int dy = 0; dy < 4; ++dy) {
                const unsigned int* pr = p + dy * (kW * 128);
#pragma unroll
                for (int dx = 0; dx < 4; ++dx) {
                    const unsigned int u = pr[dx * 128];
                    const float e = __uint_as_float(u << 16);          // even ch
                    const float o = __uint_as_float(u & 0xffff0000u);  // odd ch
                    acc0 += wq[dy][dx] * e;
                    acc1 += wq[dy][dx] * o;
                }
            }
            otile[lane * 2    ][bin] = acc0;
            otile[lane * 2 + 1][bin] = acc1;
        }
    }
    __syncthreads();

    // phase 3: coalesced stores, lane = bin column
#pragma unroll 4
    for (int j = 0; j < 32; ++j) {
        const int row = j * 4 + wv;          // local channel 0..127
        if (lane < ROI_NBIN) {
            out[((size_t)k * kC + half * 128 + row) * ROI_NBIN + lane] =
                otile[row][lane];
        }
    }
}

// ---------------- Fallback (round-2 kernel, NCHW direct) -------------------
constexpr int kCPW = 8;
constexpr int kWPK = kC / kCPW;

__global__ __launch_bounds__(256) void roi_align_fwd(
    const float* __restrict__ feat,
    const float* __restrict__ rois,
    float* __restrict__ out,
    int K)
{
    const int lane = threadIdx.x & 63;
    const int wave = threadIdx.x >> 6;
    const int wg   = blockIdx.x * 4 + wave;
    int k  = wg >> 5;
    int cg = wg & (kWPK - 1);
    if (k >= K) return;
    k  = __builtin_amdgcn_readfirstlane(k);
    cg = __builtin_amdgcn_readfirstlane(cg);

    const bool active = lane < ROI_NBIN;
    const int  bin = active ? lane : (ROI_NBIN - 1);
    const int  ph = bin / ROI_PW;
    const int  pw = bin - ph * ROI_PW;

    const float* r = rois + (size_t)k * 5;
    const int   bidx = (int)r[0];
    const float x1 = r[1] * ROI_SCALE;
    const float y1 = r[2] * ROI_SCALE;
    const float x2 = r[3] * ROI_SCALE;
    const float y2 = r[4] * ROI_SCALE;
    const float bw2 = fmaxf(x2 - x1, 1.0f) * (0.5f / ROI_PW);
    const float bh2 = fmaxf(y2 - y1, 1.0f) * (0.5f / ROI_PH);

    const float gy0 = y1 + ((float)(2 * ph) + 0.5f) * bh2;
    const float gy1 = y1 + ((float)(2 * ph) + 1.5f) * bh2;
    const float gx0 = x1 + ((float)(2 * pw) + 0.5f) * bw2;
    const float gx1 = x1 + ((float)(2 * pw) + 1.5f) * bw2;

    int ybase, xbase;
    float wy[4], wx[4];
    axis_weights(gy0, gy1, kH, ybase, wy);
    axis_weights(gx0, gx1, kW, xbase, wx);

    float wgt[4][4];
#pragma unroll
    for (int dy = 0; dy < 4; ++dy) {
        const float wyq = wy[dy] * 0.25f;
#pragma unroll
        for (int dx = 0; dx < 4; ++dx) wgt[dy][dx] = wyq * wx[dx];
    }

    const float* plane0 = feat + ((size_t)bidx * kC + (size_t)cg * kCPW) * kPlane
                               + (size_t)(ybase * kW + xbase);
    float* outp = out + ((size_t)k * kC + (size_t)cg * kCPW) * ROI_NBIN + bin;

#pragma unroll
    for (int ci = 0; ci < kCPW; ++ci) {
        const float* __restrict__ p = plane0 + (size_t)ci * kPlane;
        const f32x4 r0 = ld4(p);
        const f32x4 r1 = ld4(p + kW);
        const f32x4 r2 = ld4(p + 2 * kW);
        const f32x4 r3 = ld4(p + 3 * kW);
        float acc = 0.0f;
#pragma unroll
        for (int dx = 0; dx < 4; ++dx) acc += wgt[0][dx] * r0[dx];
#pragma unroll
        for (int dx = 0; dx < 4; ++dx) acc += wgt[1][dx] * r1[dx];
#pragma unroll
        for (int dx = 0; dx < 4; ++dx) acc += wgt[2][dx] * r2[dx];
#pragma unroll
        for (int dx = 0; dx < 4; ++dx) acc += wgt[3][dx] * r3[dx];
        if (active) outp[ci * ROI_NBIN] = acc;
    }
}

extern "C" void kernel_launch(void* const* d_in, const int* in_sizes, int n_in,
                              void* d_out, int out_size, void* d_ws, size_t ws_size,
                              hipStream_t stream) {
    const float* feat = (const float*)d_in[0];
    const float* rois = (const float*)d_in[1];
    float* out = (float*)d_out;
    const int K = in_sizes[1] / 5;               // 1000

    const size_t ws_needed = (size_t)kB * kPlane * kC * 2;  // 10.24 MB bf16 NHWC
    if (ws_size >= ws_needed) {
        unsigned int* wsp = (unsigned int*)d_ws;
        nchw_to_nhwc_bf16<<<kB * kPixGroups, 256, 0, stream>>>(feat, wsp);
        roi_align_nhwc<<<K * 2, 256, 0, stream>>>(wsp, rois, out, K);
    } else {
        const int total_waves = K * kWPK;
        const int blocks = (total_waves + 3) / 4;
        roi_align_fwd<<<blocks, 256, 0, stream>>>(feat, rois, out, K);
    }
}